// Round 2
// baseline (602.950 us; speedup 1.0000x reference)
//
#include <hip/hip_runtime.h>
#include <cstdint>
#include <cstddef>

typedef _Float16 f16;
typedef _Float16 half8 __attribute__((ext_vector_type(8)));
typedef float floatx4 __attribute__((ext_vector_type(4)));

// async global->LDS, 16B per lane. LDS dest = wave-uniform base + lane*16.
__device__ __forceinline__ void gload_lds16(const void* g, void* l) {
    __builtin_amdgcn_global_load_lds(
        (const __attribute__((address_space(1))) void*)g,
        (__attribute__((address_space(3))) void*)l,
        16, 0, 0);
}

// ---------------- K0a: f32 -> f16 convert (8 elems/thread) ----------------
__global__ void k_cvt(const float* __restrict__ src, f16* __restrict__ dst, int n8) {
    int i = blockIdx.x * blockDim.x + threadIdx.x;
    if (i >= n8) return;
    const float4* s = (const float4*)src + 2 * (size_t)i;
    float4 a = s[0], b = s[1];
    half8 h;
    h[0] = (f16)a.x; h[1] = (f16)a.y; h[2] = (f16)a.z; h[3] = (f16)a.w;
    h[4] = (f16)b.x; h[5] = (f16)b.y; h[6] = (f16)b.z; h[7] = (f16)b.w;
    ((half8*)dst)[i] = h;
}

// ------- K0b: h_s f32 -> h_s16 (same layout) + h_sT16 (d-major transpose) -------
__global__ void k_hs(const float* __restrict__ hs, f16* __restrict__ hs16, f16* __restrict__ hsT) {
    // grid: B * (S/64) * (D/64) = 4*64*4 = 1024
    int id = blockIdx.x;
    int dt = id & 3;
    int st = (id >> 2) & 63;
    int b  = id >> 8;
    __shared__ f16 tile[64][65];
    int t = threadIdx.x;
    int s0 = st * 64, d0 = dt * 64;
#pragma unroll
    for (int i = 0; i < 16; i++) {
        int e = t + i * 256;
        int r = e >> 6, c = e & 63;
        float v = hs[((size_t)(b * 4096 + s0 + r)) * 256 + d0 + c];
        f16 hv = (f16)v;
        hs16[((size_t)(b * 4096 + s0 + r)) * 256 + d0 + c] = hv;
        tile[r][c] = hv;
    }
    __syncthreads();
#pragma unroll
    for (int i = 0; i < 16; i++) {
        int e = t + i * 256;
        int r = e >> 6, c = e & 63;  // r = d-local, c = s-local
        hsT[((size_t)(b * 256 + d0 + r)) * 4096 + s0 + c] = tile[c][r];
    }
}

// ---------------- K1: energy = h_s @ W^T  (M=4096 s, N=256 t, K=256) -> f16 ----------------
__global__ __launch_bounds__(256, 2) void k_energy(
    const f16* __restrict__ A,    // h_s16: B*4096*256 (K-contig)
    const f16* __restrict__ Bt,   // W16: 256*256 (N,K) row-major
    f16* __restrict__ C)          // energy16: B*4096*256 (s-major, tgt-contig)
{
    int id = blockIdx.x;
    int tn = id & 1, tm = (id >> 1) & 31, b = id >> 6;
    const f16* Ab = A + (size_t)b * 4096 * 256;

    __shared__ __align__(16) f16 As[128 * 64];
    __shared__ __align__(16) f16 Bs[128 * 64];

    int tid = threadIdx.x;
    int wave = tid >> 6, lane = tid & 63;
    int wr = wave >> 1, wc = wave & 1;
    int lm = lane & 15, lq = lane >> 4;

    floatx4 acc[4][4] = {};
    int r0 = tm * 128, c0 = tn * 128;

    for (int k0 = 0; k0 < 256; k0 += 64) {
#pragma unroll
        for (int i = 0; i < 4; i++) {
            int rbase = wave * 32 + i * 8;
            int row = rbase + (lane >> 3);
            gload_lds16(Ab + (size_t)(r0 + row) * 256 + k0 + (lane & 7) * 8, &As[rbase * 64]);
            gload_lds16(Bt + (size_t)(c0 + row) * 256 + k0 + (lane & 7) * 8, &Bs[rbase * 64]);
        }
        __syncthreads();
        half8 af[4][2], bf[4][2];
#pragma unroll
        for (int mi = 0; mi < 4; mi++)
#pragma unroll
            for (int kk = 0; kk < 2; kk++) {
                af[mi][kk] = *(const half8*)&As[(wr * 64 + mi * 16 + lm) * 64 + kk * 32 + lq * 8];
                bf[mi][kk] = *(const half8*)&Bs[(wc * 64 + mi * 16 + lm) * 64 + kk * 32 + lq * 8];
            }
#pragma unroll
        for (int kk = 0; kk < 2; kk++)
#pragma unroll
            for (int mi = 0; mi < 4; mi++)
#pragma unroll
                for (int ni = 0; ni < 4; ni++)
                    acc[mi][ni] = __builtin_amdgcn_mfma_f32_16x16x32_f16(af[mi][kk], bf[ni][kk], acc[mi][ni], 0, 0, 0);
        __syncthreads();
    }
#pragma unroll
    for (int mi = 0; mi < 4; mi++)
#pragma unroll
        for (int ni = 0; ni < 4; ni++)
#pragma unroll
            for (int r = 0; r < 4; r++) {
                int row = r0 + wr * 64 + mi * 16 + lq * 4 + r;
                int col = c0 + wc * 64 + ni * 16 + lm;
                C[(size_t)(b * 4096 + row) * 256 + col] = (f16)acc[mi][ni][r];
            }
}

// ---------------- K2: scores = h_t @ energy^T + mask (M=T, N=S, K=256) -> raw f32 ----------------
__global__ __launch_bounds__(256, 2) void k_scores(
    const f16* __restrict__ A,    // h_t16
    const f16* __restrict__ Bt,   // energy16
    const int* __restrict__ ms,   // B*S
    float* __restrict__ C)        // d_out scores region: B*T*S
{
    int id = blockIdx.x;
    int tn = id & 31, tm = (id >> 5) & 31, b = id >> 10;
    const f16* Ab = A + (size_t)b * 4096 * 256;
    const f16* Bb = Bt + (size_t)b * 4096 * 256;

    __shared__ __align__(16) f16 As[128 * 64];
    __shared__ __align__(16) f16 Bs[128 * 64];

    int tid = threadIdx.x;
    int wave = tid >> 6, lane = tid & 63;
    int wr = wave >> 1, wc = wave & 1;
    int lm = lane & 15, lq = lane >> 4;

    floatx4 acc[4][4] = {};
    int r0 = tm * 128, c0 = tn * 128;

    for (int k0 = 0; k0 < 256; k0 += 64) {
#pragma unroll
        for (int i = 0; i < 4; i++) {
            int rbase = wave * 32 + i * 8;
            int row = rbase + (lane >> 3);
            gload_lds16(Ab + (size_t)(r0 + row) * 256 + k0 + (lane & 7) * 8, &As[rbase * 64]);
            gload_lds16(Bb + (size_t)(c0 + row) * 256 + k0 + (lane & 7) * 8, &Bs[rbase * 64]);
        }
        __syncthreads();
        half8 af[4][2], bf[4][2];
#pragma unroll
        for (int mi = 0; mi < 4; mi++)
#pragma unroll
            for (int kk = 0; kk < 2; kk++) {
                af[mi][kk] = *(const half8*)&As[(wr * 64 + mi * 16 + lm) * 64 + kk * 32 + lq * 8];
                bf[mi][kk] = *(const half8*)&Bs[(wc * 64 + mi * 16 + lm) * 64 + kk * 32 + lq * 8];
            }
#pragma unroll
        for (int kk = 0; kk < 2; kk++)
#pragma unroll
            for (int mi = 0; mi < 4; mi++)
#pragma unroll
                for (int ni = 0; ni < 4; ni++)
                    acc[mi][ni] = __builtin_amdgcn_mfma_f32_16x16x32_f16(af[mi][kk], bf[ni][kk], acc[mi][ni], 0, 0, 0);
        __syncthreads();
    }
    // epilogue: mask -> -1e10 (clamped masked value), raw f32 store
#pragma unroll
    for (int ni = 0; ni < 4; ni++) {
        int col = c0 + wc * 64 + ni * 16 + lm;
        int m = ms[b * 4096 + col];
#pragma unroll
        for (int mi = 0; mi < 4; mi++)
#pragma unroll
            for (int r = 0; r < 4; r++) {
                int row = r0 + wr * 64 + mi * 16 + lq * 4 + r;
                float v = m ? acc[mi][ni][r] : -1.0e10f;
                C[(size_t)(b * 4096 + row) * 4096 + col] = v;
            }
    }
}

// ---------------- K3: per-row online (max, sumexp). 1 block per row ----------------
__global__ __launch_bounds__(256) void k_stats(const float* __restrict__ Sc,
                                               float* __restrict__ rmax, float* __restrict__ rsum) {
    int row = blockIdx.x;  // b*4096 + t
    int tid = threadIdx.x;
    const float* p = Sc + (size_t)row * 4096 + tid * 16;
    float m = -1e30f, l = 0.f;
#pragma unroll
    for (int i = 0; i < 4; i++) {
        float4 v = ((const float4*)p)[i];
        float mx = fmaxf(fmaxf(v.x, v.y), fmaxf(v.z, v.w));
        float nm = fmaxf(m, mx);
        l = l * __expf(m - nm) + __expf(v.x - nm) + __expf(v.y - nm) + __expf(v.z - nm) + __expf(v.w - nm);
        m = nm;
    }
#pragma unroll
    for (int off = 1; off < 64; off <<= 1) {
        float m2 = __shfl_xor(m, off, 64);
        float l2 = __shfl_xor(l, off, 64);
        float nm = fmaxf(m, m2);
        l = l * __expf(m - nm) + l2 * __expf(m2 - nm);
        m = nm;
    }
    __shared__ float sm[4], sl[4];
    if ((tid & 63) == 0) { sm[tid >> 6] = m; sl[tid >> 6] = l; }
    __syncthreads();
    if (tid == 0) {
        m = sm[0]; l = sl[0];
#pragma unroll
        for (int w = 1; w < 4; w++) {
            float nm = fmaxf(m, sm[w]);
            l = l * __expf(m - nm) + sl[w] * __expf(sm[w] - nm);
            m = nm;
        }
        rmax[row] = m;
        rsum[row] = l;
    }
}

// ------- K4: normalize P (race-free) + context partial GEMM (split-K over s) -------
// block: 128 t-rows x 256 d-cols, s-range 1024. grid = B*32*4 = 512.
// Waves (wr, wc=0) and (wr, wc=1) read the SAME raw Sc words; all reads complete
// before the barrier, then ONLY wc==0 writes the normalized values back.
__global__ __launch_bounds__(256, 2) void k_ctx(
    const f16* __restrict__ BtT,   // h_sT16: B*256*4096
    float* __restrict__ Sc,        // scores (raw in -> normalized out)
    const float* __restrict__ rmax,
    const float* __restrict__ rsum,
    float* __restrict__ part)      // 4 * B*4096*256
{
    int id = blockIdx.x;
    int ks = id & 3, tt = (id >> 2) & 31, b = id >> 7;
    int tid = threadIdx.x;
    int wave = tid >> 6, lane = tid & 63;
    int wr = wave >> 1, wc = wave & 1;
    int lm = lane & 15, lq = lane >> 4;

    __shared__ __align__(16) f16 Bs[256 * 64];  // 32KB

    int t0 = tt * 128;
    const f16* Bb = BtT + (size_t)b * 256 * 4096;

    float mrow[4], rinv[4];
    size_t rowbase[4];
#pragma unroll
    for (int mi = 0; mi < 4; mi++) {
        int row = t0 + wr * 64 + mi * 16 + lm;
        int gr = b * 4096 + row;
        mrow[mi] = rmax[gr];
        rinv[mi] = 1.0f / rsum[gr];
        rowbase[mi] = (size_t)gr * 4096;
    }

    floatx4 acc[4][8] = {};
    int sbeg = ks * 1024;

    for (int it = 0; it < 16; it++) {
        int s0 = sbeg + it * 64;
        // stage h_sT tile: 256 d-rows x 64 s-halves (async)
#pragma unroll
        for (int i = 0; i < 8; i++) {
            int rbase = wave * 64 + i * 8;
            gload_lds16(Bb + (size_t)(rbase + (lane >> 3)) * 4096 + s0 + (lane & 7) * 8, &Bs[rbase * 64]);
        }
        // A-fragments straight from global raw scores; normalize into registers only
        half8 af[4][2];
#pragma unroll
        for (int mi = 0; mi < 4; mi++)
#pragma unroll
            for (int kk = 0; kk < 2; kk++) {
                int sidx = s0 + kk * 32 + lq * 8;
                const float* p = Sc + rowbase[mi] + sidx;
                float4 v0 = ((const float4*)p)[0];
                float4 v1 = ((const float4*)p)[1];
                half8 h;
                h[0] = (f16)(__expf(v0.x - mrow[mi]) * rinv[mi]);
                h[1] = (f16)(__expf(v0.y - mrow[mi]) * rinv[mi]);
                h[2] = (f16)(__expf(v0.z - mrow[mi]) * rinv[mi]);
                h[3] = (f16)(__expf(v0.w - mrow[mi]) * rinv[mi]);
                h[4] = (f16)(__expf(v1.x - mrow[mi]) * rinv[mi]);
                h[5] = (f16)(__expf(v1.y - mrow[mi]) * rinv[mi]);
                h[6] = (f16)(__expf(v1.z - mrow[mi]) * rinv[mi]);
                h[7] = (f16)(__expf(v1.w - mrow[mi]) * rinv[mi]);
                af[mi][kk] = h;
            }
        __syncthreads();  // all raw reads done + LDS staged
        // write back normalized scores (once per location; f16-rounded, err<=5e-4)
        if (wc == 0) {
#pragma unroll
            for (int mi = 0; mi < 4; mi++)
#pragma unroll
                for (int kk = 0; kk < 2; kk++) {
                    int sidx = s0 + kk * 32 + lq * 8;
                    float* p = Sc + rowbase[mi] + sidx;
                    half8 h = af[mi][kk];
                    float4 w0 = make_float4((float)h[0], (float)h[1], (float)h[2], (float)h[3]);
                    float4 w1 = make_float4((float)h[4], (float)h[5], (float)h[6], (float)h[7]);
                    ((float4*)p)[0] = w0;
                    ((float4*)p)[1] = w1;
                }
        }
#pragma unroll
        for (int kk = 0; kk < 2; kk++)
#pragma unroll
            for (int ni = 0; ni < 8; ni++) {
                half8 bf = *(const half8*)&Bs[(wc * 128 + ni * 16 + lm) * 64 + kk * 32 + lq * 8];
#pragma unroll
                for (int mi = 0; mi < 4; mi++)
                    acc[mi][ni] = __builtin_amdgcn_mfma_f32_16x16x32_f16(af[mi][kk], bf, acc[mi][ni], 0, 0, 0);
            }
        __syncthreads();
    }

    float* P = part + (size_t)ks * 4194304 + (size_t)b * 1048576;
#pragma unroll
    for (int mi = 0; mi < 4; mi++)
#pragma unroll
        for (int ni = 0; ni < 8; ni++)
#pragma unroll
            for (int r = 0; r < 4; r++) {
                int row = t0 + wr * 64 + mi * 16 + lq * 4 + r;
                int col = wc * 128 + ni * 16 + lm;
                P[(size_t)row * 256 + col] = acc[mi][ni][r];
            }
}

// ---------------- K5: reduce 4 split-K partials -> context ----------------
__global__ void k_red(const float* __restrict__ part, float* __restrict__ out) {
    size_t i = (size_t)blockIdx.x * 256 + threadIdx.x;  // float4 index, N4 = 1048576
    const float4* p = (const float4*)part;
    float4 a = p[i];
    float4 b = p[i + 1048576];
    float4 c = p[i + 2097152];
    float4 d = p[i + 3145728];
    a.x += b.x + c.x + d.x;
    a.y += b.y + c.y + d.y;
    a.z += b.z + c.z + d.z;
    a.w += b.w + c.w + d.w;
    ((float4*)out)[i] = a;
}

extern "C" void kernel_launch(void* const* d_in, const int* in_sizes, int n_in,
                              void* d_out, int out_size, void* d_ws, size_t ws_size,
                              hipStream_t stream) {
    const float* h_t = (const float*)d_in[0];   // 4*4096*256
    const float* h_s = (const float*)d_in[1];   // 4*4096*256
    const int*   m_s = (const int*)d_in[2];     // 4*4096
    const float* W   = (const float*)d_in[3];   // 256*256

    float* out = (float*)d_out;
    char* ws = (char*)d_ws;
    f16* h_t16 = (f16*)(ws);
    f16* h_s16 = (f16*)(ws + 8388608);
    f16* h_sT  = (f16*)(ws + 16777216);
    f16* en16  = (f16*)(ws + 25165824);
    f16* W16   = (f16*)(ws + 33554432);
    float* rmax = (float*)(ws + 33685504);
    float* rsum = (float*)(ws + 33751040);
    float* part = (float*)(ws + 33816576);   // 4 * 16.78MB

    float* ctx = out;              // 4*4096*256 = 4194304
    float* sc  = out + 4194304;    // 4*4096*4096

    k_cvt<<<2048, 256, 0, stream>>>(h_t, h_t16, 524288);
    k_cvt<<<32, 256, 0, stream>>>(W, W16, 8192);
    k_hs<<<1024, 256, 0, stream>>>(h_s, h_s16, h_sT);
    k_energy<<<256, 256, 0, stream>>>(h_s16, W16, en16);
    k_scores<<<4096, 256, 0, stream>>>(h_t16, en16, m_s, sc);
    k_stats<<<16384, 256, 0, stream>>>(sc, rmax, rsum);
    k_ctx<<<512, 256, 0, stream>>>(h_sT, sc, rmax, rsum, part);
    k_red<<<4096, 256, 0, stream>>>(part, ctx);
}

// Round 3
// 570.513 us; speedup vs baseline: 1.0569x; 1.0569x over previous
//
#include <hip/hip_runtime.h>
#include <cstdint>
#include <cstddef>

typedef _Float16 f16;
typedef _Float16 half8 __attribute__((ext_vector_type(8)));
typedef float floatx4 __attribute__((ext_vector_type(4)));

// async global->LDS, 16B per lane. LDS dest = wave-uniform base + lane*16.
__device__ __forceinline__ void gload_lds16(const void* g, void* l) {
    __builtin_amdgcn_global_load_lds(
        (const __attribute__((address_space(1))) void*)g,
        (__attribute__((address_space(3))) void*)l,
        16, 0, 0);
}

// ---------------- K0a: f32 -> f16 convert (8 elems/thread) ----------------
__global__ void k_cvt(const float* __restrict__ src, f16* __restrict__ dst, int n8) {
    int i = blockIdx.x * blockDim.x + threadIdx.x;
    if (i >= n8) return;
    const float4* s = (const float4*)src + 2 * (size_t)i;
    float4 a = s[0], b = s[1];
    half8 h;
    h[0] = (f16)a.x; h[1] = (f16)a.y; h[2] = (f16)a.z; h[3] = (f16)a.w;
    h[4] = (f16)b.x; h[5] = (f16)b.y; h[6] = (f16)b.z; h[7] = (f16)b.w;
    ((half8*)dst)[i] = h;
}

// ------- K0b: h_s f32 -> h_s16 (same layout) + h_sT16 (d-major transpose) -------
__global__ void k_hs(const float* __restrict__ hs, f16* __restrict__ hs16, f16* __restrict__ hsT) {
    // grid: B * (S/64) * (D/64) = 4*64*4 = 1024
    int id = blockIdx.x;
    int dt = id & 3;
    int st = (id >> 2) & 63;
    int b  = id >> 8;
    __shared__ f16 tile[64][65];
    int t = threadIdx.x;
    int s0 = st * 64, d0 = dt * 64;
#pragma unroll
    for (int i = 0; i < 16; i++) {
        int e = t + i * 256;
        int r = e >> 6, c = e & 63;
        float v = hs[((size_t)(b * 4096 + s0 + r)) * 256 + d0 + c];
        f16 hv = (f16)v;
        hs16[((size_t)(b * 4096 + s0 + r)) * 256 + d0 + c] = hv;
        tile[r][c] = hv;
    }
    __syncthreads();
#pragma unroll
    for (int i = 0; i < 16; i++) {
        int e = t + i * 256;
        int r = e >> 6, c = e & 63;  // r = d-local, c = s-local
        hsT[((size_t)(b * 256 + d0 + r)) * 4096 + s0 + c] = tile[c][r];
    }
}

// ---------------- K1: energy = h_s @ W^T  (M=4096 s, N=256 t, K=256) -> f16 ----------------
__global__ __launch_bounds__(256, 2) void k_energy(
    const f16* __restrict__ A,    // h_s16: B*4096*256 (K-contig)
    const f16* __restrict__ Bt,   // W16: 256*256 (N,K) row-major
    f16* __restrict__ C)          // energy16: B*4096*256 (s-major, tgt-contig)
{
    int id = blockIdx.x;
    int tn = id & 1, tm = (id >> 1) & 31, b = id >> 6;
    const f16* Ab = A + (size_t)b * 4096 * 256;

    __shared__ __align__(16) f16 As[128 * 64];
    __shared__ __align__(16) f16 Bs[128 * 64];

    int tid = threadIdx.x;
    int wave = tid >> 6, lane = tid & 63;
    int wr = wave >> 1, wc = wave & 1;
    int lm = lane & 15, lq = lane >> 4;

    floatx4 acc[4][4] = {};
    int r0 = tm * 128, c0 = tn * 128;

    for (int k0 = 0; k0 < 256; k0 += 64) {
#pragma unroll
        for (int i = 0; i < 4; i++) {
            int rbase = wave * 32 + i * 8;
            int row = rbase + (lane >> 3);
            gload_lds16(Ab + (size_t)(r0 + row) * 256 + k0 + (lane & 7) * 8, &As[rbase * 64]);
            gload_lds16(Bt + (size_t)(c0 + row) * 256 + k0 + (lane & 7) * 8, &Bs[rbase * 64]);
        }
        __syncthreads();
        half8 af[4][2], bf[4][2];
#pragma unroll
        for (int mi = 0; mi < 4; mi++)
#pragma unroll
            for (int kk = 0; kk < 2; kk++) {
                af[mi][kk] = *(const half8*)&As[(wr * 64 + mi * 16 + lm) * 64 + kk * 32 + lq * 8];
                bf[mi][kk] = *(const half8*)&Bs[(wc * 64 + mi * 16 + lm) * 64 + kk * 32 + lq * 8];
            }
#pragma unroll
        for (int kk = 0; kk < 2; kk++)
#pragma unroll
            for (int mi = 0; mi < 4; mi++)
#pragma unroll
                for (int ni = 0; ni < 4; ni++)
                    acc[mi][ni] = __builtin_amdgcn_mfma_f32_16x16x32_f16(af[mi][kk], bf[ni][kk], acc[mi][ni], 0, 0, 0);
        __syncthreads();
    }
#pragma unroll
    for (int mi = 0; mi < 4; mi++)
#pragma unroll
        for (int ni = 0; ni < 4; ni++)
#pragma unroll
            for (int r = 0; r < 4; r++) {
                int row = r0 + wr * 64 + mi * 16 + lq * 4 + r;
                int col = c0 + wc * 64 + ni * 16 + lm;
                C[(size_t)(b * 4096 + row) * 256 + col] = (f16)acc[mi][ni][r];
            }
}

// -------- K2: scores = h_t @ energy^T + mask -> raw f32; fused row sumexp atomics --------
__global__ __launch_bounds__(256, 2) void k_scores(
    const f16* __restrict__ A,    // h_t16
    const f16* __restrict__ Bt,   // energy16
    const int* __restrict__ ms,   // B*S
    float* __restrict__ C,        // d_out scores region: B*T*S (raw masked scores)
    float* __restrict__ rsum)     // B*T, pre-zeroed; Σ_s exp(s) per row (no max shift)
{
    int id = blockIdx.x;
    int tn = id & 31, tm = (id >> 5) & 31, b = id >> 10;
    const f16* Ab = A + (size_t)b * 4096 * 256;
    const f16* Bb = Bt + (size_t)b * 4096 * 256;

    __shared__ __align__(16) f16 As[128 * 64];
    __shared__ __align__(16) f16 Bs[128 * 64];

    int tid = threadIdx.x;
    int wave = tid >> 6, lane = tid & 63;
    int wr = wave >> 1, wc = wave & 1;
    int lm = lane & 15, lq = lane >> 4;

    floatx4 acc[4][4] = {};
    int r0 = tm * 128, c0 = tn * 128;

    for (int k0 = 0; k0 < 256; k0 += 64) {
#pragma unroll
        for (int i = 0; i < 4; i++) {
            int rbase = wave * 32 + i * 8;
            int row = rbase + (lane >> 3);
            gload_lds16(Ab + (size_t)(r0 + row) * 256 + k0 + (lane & 7) * 8, &As[rbase * 64]);
            gload_lds16(Bb + (size_t)(c0 + row) * 256 + k0 + (lane & 7) * 8, &Bs[rbase * 64]);
        }
        __syncthreads();
        half8 af[4][2], bf[4][2];
#pragma unroll
        for (int mi = 0; mi < 4; mi++)
#pragma unroll
            for (int kk = 0; kk < 2; kk++) {
                af[mi][kk] = *(const half8*)&As[(wr * 64 + mi * 16 + lm) * 64 + kk * 32 + lq * 8];
                bf[mi][kk] = *(const half8*)&Bs[(wc * 64 + mi * 16 + lm) * 64 + kk * 32 + lq * 8];
            }
#pragma unroll
        for (int kk = 0; kk < 2; kk++)
#pragma unroll
            for (int mi = 0; mi < 4; mi++)
#pragma unroll
                for (int ni = 0; ni < 4; ni++)
                    acc[mi][ni] = __builtin_amdgcn_mfma_f32_16x16x32_f16(af[mi][kk], bf[ni][kk], acc[mi][ni], 0, 0, 0);
        __syncthreads();
    }
    // epilogue: mask -> -1e10, store raw f32, accumulate row partial sums of exp
    float rs[4][4] = {};  // [mi][r], this wave's 64-col partial per row
#pragma unroll
    for (int ni = 0; ni < 4; ni++) {
        int col = c0 + wc * 64 + ni * 16 + lm;
        int m = ms[b * 4096 + col];
#pragma unroll
        for (int mi = 0; mi < 4; mi++)
#pragma unroll
            for (int r = 0; r < 4; r++) {
                int row = r0 + wr * 64 + mi * 16 + lq * 4 + r;
                float v = m ? acc[mi][ni][r] : -1.0e10f;
                C[(size_t)(b * 4096 + row) * 4096 + col] = v;
                rs[mi][r] += __expf(v);   // expf(-1e10) == 0 exactly
            }
    }
    // reduce across the 16 lm-lanes (lanes lq*16+lm are contiguous groups of 16)
#pragma unroll
    for (int mi = 0; mi < 4; mi++)
#pragma unroll
        for (int r = 0; r < 4; r++) {
            float v = rs[mi][r];
#pragma unroll
            for (int off = 1; off < 16; off <<= 1)
                v += __shfl_xor(v, off, 16);
            if (lm == 0) {
                int row = r0 + wr * 64 + mi * 16 + lq * 4 + r;
                atomicAdd(&rsum[b * 4096 + row], v);
            }
        }
}

// ------- K4: normalize P + write p (f32) + context partial GEMM (split-K over s) -------
// block: 128 t-rows x 256 d-cols, s-range 1024. grid = B*32*4 = 512.
// Each wave owns 32 distinct rows x all 256 cols: no duplicated Sc reads, single writer.
__global__ __launch_bounds__(256, 2) void k_ctx(
    const f16* __restrict__ BtT,   // h_sT16: B*256*4096
    float* __restrict__ Sc,        // scores (raw in -> normalized out, in place)
    const float* __restrict__ rsum,
    float* __restrict__ part)      // 4 * B*4096*256
{
    int id = blockIdx.x;
    int ks = id & 3, tt = (id >> 2) & 31, b = id >> 7;
    int tid = threadIdx.x;
    int wave = tid >> 6, lane = tid & 63;
    int lm = lane & 15, lq = lane >> 4;

    __shared__ __align__(16) f16 Bs[256 * 64];  // 32KB

    int t0 = tt * 128;
    const f16* Bb = BtT + (size_t)b * 256 * 4096;

    float rinv[2];
    size_t rowbase[2];
#pragma unroll
    for (int mi = 0; mi < 2; mi++) {
        int row = t0 + wave * 32 + mi * 16 + lm;
        int gr = b * 4096 + row;
        rinv[mi] = 1.0f / rsum[gr];
        rowbase[mi] = (size_t)gr * 4096;
    }

    floatx4 acc[2][16] = {};
    int sbeg = ks * 1024;

    for (int it = 0; it < 16; it++) {
        int s0 = sbeg + it * 64;
        // stage h_sT tile: 256 d-rows x 64 s (async)
#pragma unroll
        for (int i = 0; i < 8; i++) {
            int rbase = wave * 64 + i * 8;
            gload_lds16(Bb + (size_t)(rbase + (lane >> 3)) * 4096 + s0 + (lane & 7) * 8, &Bs[rbase * 64]);
        }
        // normalize raw scores in registers; write f32 p in place; keep f16 frags
        half8 af[2][2];
#pragma unroll
        for (int mi = 0; mi < 2; mi++)
#pragma unroll
            for (int kk = 0; kk < 2; kk++) {
                int sidx = s0 + kk * 32 + lq * 8;
                float* p = Sc + rowbase[mi] + sidx;
                float4 v0 = ((const float4*)p)[0];
                float4 v1 = ((const float4*)p)[1];
                float p0 = __expf(v0.x) * rinv[mi];
                float p1 = __expf(v0.y) * rinv[mi];
                float p2 = __expf(v0.z) * rinv[mi];
                float p3 = __expf(v0.w) * rinv[mi];
                float p4 = __expf(v1.x) * rinv[mi];
                float p5 = __expf(v1.y) * rinv[mi];
                float p6 = __expf(v1.z) * rinv[mi];
                float p7 = __expf(v1.w) * rinv[mi];
                ((float4*)p)[0] = make_float4(p0, p1, p2, p3);
                ((float4*)p)[1] = make_float4(p4, p5, p6, p7);
                half8 h;
                h[0] = (f16)p0; h[1] = (f16)p1; h[2] = (f16)p2; h[3] = (f16)p3;
                h[4] = (f16)p4; h[5] = (f16)p5; h[6] = (f16)p6; h[7] = (f16)p7;
                af[mi][kk] = h;
            }
        __syncthreads();  // LDS staged
#pragma unroll
        for (int kk = 0; kk < 2; kk++)
#pragma unroll
            for (int ni = 0; ni < 16; ni++) {
                half8 bf = *(const half8*)&Bs[(ni * 16 + lm) * 64 + kk * 32 + lq * 8];
#pragma unroll
                for (int mi = 0; mi < 2; mi++)
                    acc[mi][ni] = __builtin_amdgcn_mfma_f32_16x16x32_f16(af[mi][kk], bf, acc[mi][ni], 0, 0, 0);
            }
        __syncthreads();
    }

    float* P = part + (size_t)ks * 4194304 + (size_t)b * 1048576;
#pragma unroll
    for (int mi = 0; mi < 2; mi++)
#pragma unroll
        for (int ni = 0; ni < 16; ni++)
#pragma unroll
            for (int r = 0; r < 4; r++) {
                int row = t0 + wave * 32 + mi * 16 + lq * 4 + r;
                int col = ni * 16 + lm;
                P[(size_t)row * 256 + col] = acc[mi][ni][r];
            }
}

// ---------------- K5: reduce 4 split-K partials -> context ----------------
__global__ void k_red(const float* __restrict__ part, float* __restrict__ out) {
    size_t i = (size_t)blockIdx.x * 256 + threadIdx.x;  // float4 index, N4 = 1048576
    const float4* p = (const float4*)part;
    float4 a = p[i];
    float4 b = p[i + 1048576];
    float4 c = p[i + 2097152];
    float4 d = p[i + 3145728];
    a.x += b.x + c.x + d.x;
    a.y += b.y + c.y + d.y;
    a.z += b.z + c.z + d.z;
    a.w += b.w + c.w + d.w;
    ((float4*)out)[i] = a;
}

extern "C" void kernel_launch(void* const* d_in, const int* in_sizes, int n_in,
                              void* d_out, int out_size, void* d_ws, size_t ws_size,
                              hipStream_t stream) {
    const float* h_t = (const float*)d_in[0];   // 4*4096*256
    const float* h_s = (const float*)d_in[1];   // 4*4096*256
    const int*   m_s = (const int*)d_in[2];     // 4*4096
    const float* W   = (const float*)d_in[3];   // 256*256

    float* out = (float*)d_out;
    char* ws = (char*)d_ws;
    f16* h_t16 = (f16*)(ws);
    f16* h_s16 = (f16*)(ws + 8388608);
    f16* h_sT  = (f16*)(ws + 16777216);
    f16* en16  = (f16*)(ws + 25165824);
    f16* W16   = (f16*)(ws + 33554432);
    float* rsum = (float*)(ws + 33685504);   // 16384 floats
    float* part = (float*)(ws + 33816576);   // 4 * 16.78MB

    float* ctx = out;              // 4*4096*256 = 4194304
    float* sc  = out + 4194304;    // 4*4096*4096

    hipMemsetAsync(rsum, 0, 16384 * sizeof(float), stream);
    k_cvt<<<2048, 256, 0, stream>>>(h_t, h_t16, 524288);
    k_cvt<<<32, 256, 0, stream>>>(W, W16, 8192);
    k_hs<<<1024, 256, 0, stream>>>(h_s, h_s16, h_sT);
    k_energy<<<256, 256, 0, stream>>>(h_s16, W16, en16);
    k_scores<<<4096, 256, 0, stream>>>(h_t16, en16, m_s, sc, rsum);
    k_ctx<<<512, 256, 0, stream>>>(h_sT, sc, rsum, part);
    k_red<<<4096, 256, 0, stream>>>(part, ctx);
}

// Round 4
// 542.686 us; speedup vs baseline: 1.1110x; 1.0513x over previous
//
#include <hip/hip_runtime.h>
#include <cstdint>
#include <cstddef>

typedef _Float16 f16;
typedef _Float16 half8 __attribute__((ext_vector_type(8)));
typedef float floatx4 __attribute__((ext_vector_type(4)));

// async global->LDS, 16B per lane. LDS dest = wave-uniform base + lane*16.
__device__ __forceinline__ void gload_lds16(const void* g, void* l) {
    __builtin_amdgcn_global_load_lds(
        (const __attribute__((address_space(1))) void*)g,
        (__attribute__((address_space(3))) void*)l,
        16, 0, 0);
}

// ---------------- K0a: f32 -> f16 convert (8 elems/thread) ----------------
__global__ void k_cvt(const float* __restrict__ src, f16* __restrict__ dst, int n8) {
    int i = blockIdx.x * blockDim.x + threadIdx.x;
    if (i >= n8) return;
    const float4* s = (const float4*)src + 2 * (size_t)i;
    float4 a = s[0], b = s[1];
    half8 h;
    h[0] = (f16)a.x; h[1] = (f16)a.y; h[2] = (f16)a.z; h[3] = (f16)a.w;
    h[4] = (f16)b.x; h[5] = (f16)b.y; h[6] = (f16)b.z; h[7] = (f16)b.w;
    ((half8*)dst)[i] = h;
}

// ------- K0b: h_s f32 -> h_s16 (same layout) + h_sT16 (d-major transpose) -------
__global__ void k_hs(const float* __restrict__ hs, f16* __restrict__ hs16, f16* __restrict__ hsT) {
    // grid: B * (S/64) * (D/64) = 4*64*4 = 1024
    int id = blockIdx.x;
    int dt = id & 3;
    int st = (id >> 2) & 63;
    int b  = id >> 8;
    __shared__ f16 tile[64][65];
    int t = threadIdx.x;
    int s0 = st * 64, d0 = dt * 64;
#pragma unroll
    for (int i = 0; i < 16; i++) {
        int e = t + i * 256;
        int r = e >> 6, c = e & 63;
        float v = hs[((size_t)(b * 4096 + s0 + r)) * 256 + d0 + c];
        f16 hv = (f16)v;
        hs16[((size_t)(b * 4096 + s0 + r)) * 256 + d0 + c] = hv;
        tile[r][c] = hv;
    }
    __syncthreads();
#pragma unroll
    for (int i = 0; i < 16; i++) {
        int e = t + i * 256;
        int r = e >> 6, c = e & 63;  // r = d-local, c = s-local
        hsT[((size_t)(b * 256 + d0 + r)) * 4096 + s0 + c] = tile[c][r];
    }
}

// ---------------- K1: energy = h_s @ W^T  (M=4096 s, N=256 t, K=256) -> f16 ----------------
__global__ __launch_bounds__(256, 2) void k_energy(
    const f16* __restrict__ A,    // h_s16: B*4096*256 (K-contig)
    const f16* __restrict__ Bt,   // W16: 256*256 (N,K) row-major
    f16* __restrict__ C)          // energy16: B*4096*256 (s-major, tgt-contig)
{
    int id = blockIdx.x;
    int tn = id & 1, tm = (id >> 1) & 31, b = id >> 6;
    const f16* Ab = A + (size_t)b * 4096 * 256;

    __shared__ __align__(16) f16 As[128 * 64];
    __shared__ __align__(16) f16 Bs[128 * 64];

    int tid = threadIdx.x;
    int wave = tid >> 6, lane = tid & 63;
    int wr = wave >> 1, wc = wave & 1;
    int lm = lane & 15, lq = lane >> 4;

    floatx4 acc[4][4] = {};
    int r0 = tm * 128, c0 = tn * 128;

    for (int k0 = 0; k0 < 256; k0 += 64) {
#pragma unroll
        for (int i = 0; i < 4; i++) {
            int rbase = wave * 32 + i * 8;
            int row = rbase + (lane >> 3);
            gload_lds16(Ab + (size_t)(r0 + row) * 256 + k0 + (lane & 7) * 8, &As[rbase * 64]);
            gload_lds16(Bt + (size_t)(c0 + row) * 256 + k0 + (lane & 7) * 8, &Bs[rbase * 64]);
        }
        __syncthreads();
        half8 af[4][2], bf[4][2];
#pragma unroll
        for (int mi = 0; mi < 4; mi++)
#pragma unroll
            for (int kk = 0; kk < 2; kk++) {
                af[mi][kk] = *(const half8*)&As[(wr * 64 + mi * 16 + lm) * 64 + kk * 32 + lq * 8];
                bf[mi][kk] = *(const half8*)&Bs[(wc * 64 + mi * 16 + lm) * 64 + kk * 32 + lq * 8];
            }
#pragma unroll
        for (int kk = 0; kk < 2; kk++)
#pragma unroll
            for (int mi = 0; mi < 4; mi++)
#pragma unroll
                for (int ni = 0; ni < 4; ni++)
                    acc[mi][ni] = __builtin_amdgcn_mfma_f32_16x16x32_f16(af[mi][kk], bf[ni][kk], acc[mi][ni], 0, 0, 0);
        __syncthreads();
    }
#pragma unroll
    for (int mi = 0; mi < 4; mi++)
#pragma unroll
        for (int ni = 0; ni < 4; ni++)
#pragma unroll
            for (int r = 0; r < 4; r++) {
                int row = r0 + wr * 64 + mi * 16 + lq * 4 + r;
                int col = c0 + wc * 64 + ni * 16 + lm;
                C[(size_t)(b * 4096 + row) * 256 + col] = (f16)acc[mi][ni][r];
            }
}

// -------- K2: scores GEMM + mask -> store e=exp(score) f32; fused row sumexp atomics --------
__global__ __launch_bounds__(256, 2) void k_scores(
    const f16* __restrict__ A,    // h_t16
    const f16* __restrict__ Bt,   // energy16
    const int* __restrict__ ms,   // B*S
    float* __restrict__ C,        // d_out scores region: B*T*S (holds exp(masked score))
    float* __restrict__ rsum)     // B*T, pre-zeroed; Σ_s exp(s) per row (no max shift)
{
    int id = blockIdx.x;
    int tn = id & 31, tm = (id >> 5) & 31, b = id >> 10;
    const f16* Ab = A + (size_t)b * 4096 * 256;
    const f16* Bb = Bt + (size_t)b * 4096 * 256;

    __shared__ __align__(16) f16 As[128 * 64];
    __shared__ __align__(16) f16 Bs[128 * 64];

    int tid = threadIdx.x;
    int wave = tid >> 6, lane = tid & 63;
    int wr = wave >> 1, wc = wave & 1;
    int lm = lane & 15, lq = lane >> 4;

    floatx4 acc[4][4] = {};
    int r0 = tm * 128, c0 = tn * 128;

    for (int k0 = 0; k0 < 256; k0 += 64) {
#pragma unroll
        for (int i = 0; i < 4; i++) {
            int rbase = wave * 32 + i * 8;
            int row = rbase + (lane >> 3);
            gload_lds16(Ab + (size_t)(r0 + row) * 256 + k0 + (lane & 7) * 8, &As[rbase * 64]);
            gload_lds16(Bb + (size_t)(c0 + row) * 256 + k0 + (lane & 7) * 8, &Bs[rbase * 64]);
        }
        __syncthreads();
        half8 af[4][2], bf[4][2];
#pragma unroll
        for (int mi = 0; mi < 4; mi++)
#pragma unroll
            for (int kk = 0; kk < 2; kk++) {
                af[mi][kk] = *(const half8*)&As[(wr * 64 + mi * 16 + lm) * 64 + kk * 32 + lq * 8];
                bf[mi][kk] = *(const half8*)&Bs[(wc * 64 + mi * 16 + lm) * 64 + kk * 32 + lq * 8];
            }
#pragma unroll
        for (int kk = 0; kk < 2; kk++)
#pragma unroll
            for (int mi = 0; mi < 4; mi++)
#pragma unroll
                for (int ni = 0; ni < 4; ni++)
                    acc[mi][ni] = __builtin_amdgcn_mfma_f32_16x16x32_f16(af[mi][kk], bf[ni][kk], acc[mi][ni], 0, 0, 0);
        __syncthreads();
    }
    // epilogue: e = mask ? exp(score) : 0; store e, accumulate row sums
    float rs[4][4] = {};  // [mi][r]
#pragma unroll
    for (int ni = 0; ni < 4; ni++) {
        int col = c0 + wc * 64 + ni * 16 + lm;
        int m = ms[b * 4096 + col];
#pragma unroll
        for (int mi = 0; mi < 4; mi++)
#pragma unroll
            for (int r = 0; r < 4; r++) {
                int row = r0 + wr * 64 + mi * 16 + lq * 4 + r;
                float e = m ? __expf(acc[mi][ni][r]) : 0.0f;
                C[(size_t)(b * 4096 + row) * 4096 + col] = e;
                rs[mi][r] += e;
            }
    }
#pragma unroll
    for (int mi = 0; mi < 4; mi++)
#pragma unroll
        for (int r = 0; r < 4; r++) {
            float v = rs[mi][r];
#pragma unroll
            for (int off = 1; off < 16; off <<= 1)
                v += __shfl_xor(v, off, 16);
            if (lm == 0) {
                int row = r0 + wr * 64 + mi * 16 + lq * 4 + r;
                atomicAdd(&rsum[b * 4096 + row], v);
            }
        }
}

// ------- K4: p = e*rinv, write p (f32, in place) + context partial GEMM (split-K) -------
// tile 128 t x 256 d, s-range 1024, grid = 4*32*4 = 512.
// LDS B-tile uses chunked-XOR layout: chunk g (s/8) at g*4096 + (row ^ 2*(g&3))*16 bytes.
// -> ds_read_b128 lands 8 lanes per 4-bank group (the b128 conflict-free floor).
// Staging keeps global_load_lds by permuting per-lane global row: row = R + (lane ^ c).
__global__ __launch_bounds__(256, 2) void k_ctx(
    const f16* __restrict__ BtT,   // h_sT16: B*256*4096
    float* __restrict__ Sc,        // e=exp(score) in -> normalized p out, in place
    const float* __restrict__ rsum,
    float* __restrict__ part)      // 4 * B*4096*256 f32
{
    int id = blockIdx.x;
    int ks = id & 3, tt = (id >> 2) & 31, b = id >> 7;
    int tid = threadIdx.x;
    int wave = tid >> 6, lane = tid & 63;
    int lm = lane & 15, lq = lane >> 4;

    __shared__ __align__(16) f16 Bs[8 * 2048];  // 32KB chunked-swizzled

    int t0 = tt * 128;
    const f16* Bb = BtT + (size_t)b * 256 * 4096;

    float rinv[2];
    size_t rowbase[2];
#pragma unroll
    for (int mi = 0; mi < 2; mi++) {
        int row = t0 + wave * 32 + mi * 16 + lm;
        int gr = b * 4096 + row;
        rinv[mi] = 1.0f / rsum[gr];
        rowbase[mi] = (size_t)gr * 4096;
    }

    // staging: this wave fills chunks g0,g1; lane's global row is XOR-permuted
    int g0 = wave * 2, g1 = wave * 2 + 1;
    int c0g = 2 * (g0 & 3), c1g = 2 * (g1 & 3);
    const f16* gp0 = Bb + (size_t)(lane ^ c0g) * 4096 + g0 * 8;
    const f16* gp1 = Bb + (size_t)(lane ^ c1g) * 4096 + g1 * 8;
    f16* lb0 = &Bs[g0 * 2048];
    f16* lb1 = &Bs[g1 * 2048];

    // read-side lane bases (f16 elements): chunk (kk*4+lq), slot (lm ^ 2lq)
    int rbk[2];
    rbk[0] = (0 * 4 + lq) * 2048 + (lm ^ (2 * lq)) * 8;
    rbk[1] = (1 * 4 + lq) * 2048 + (lm ^ (2 * lq)) * 8;

    floatx4 acc[2][16] = {};
    int sbeg = ks * 1024;

    for (int it = 0; it < 16; it++) {
        int s0 = sbeg + it * 64;
        // e-loads FIRST (so frag compute waits only on these, not the staging)
        float4 v[2][2][2];
#pragma unroll
        for (int mi = 0; mi < 2; mi++)
#pragma unroll
            for (int kk = 0; kk < 2; kk++) {
                const float* p = Sc + rowbase[mi] + s0 + kk * 32 + lq * 8;
                v[mi][kk][0] = ((const float4*)p)[0];
                v[mi][kk][1] = ((const float4*)p)[1];
            }
        // async staging (4 R-blocks x 2 chunks per wave)
#pragma unroll
        for (int R = 0; R < 256; R += 64) {
            gload_lds16(gp0 + (size_t)R * 4096 + s0, lb0 + R * 8);
            gload_lds16(gp1 + (size_t)R * 4096 + s0, lb1 + R * 8);
        }
        // normalize into f16 fragments
        half8 af[2][2];
#pragma unroll
        for (int mi = 0; mi < 2; mi++)
#pragma unroll
            for (int kk = 0; kk < 2; kk++) {
                half8 h;
                h[0] = (f16)(v[mi][kk][0].x * rinv[mi]);
                h[1] = (f16)(v[mi][kk][0].y * rinv[mi]);
                h[2] = (f16)(v[mi][kk][0].z * rinv[mi]);
                h[3] = (f16)(v[mi][kk][0].w * rinv[mi]);
                h[4] = (f16)(v[mi][kk][1].x * rinv[mi]);
                h[5] = (f16)(v[mi][kk][1].y * rinv[mi]);
                h[6] = (f16)(v[mi][kk][1].z * rinv[mi]);
                h[7] = (f16)(v[mi][kk][1].w * rinv[mi]);
                af[mi][kk] = h;
            }
        __syncthreads();  // staging visible
        // write back normalized p (f32 from f16 frags) — stores fly during MFMA phase
#pragma unroll
        for (int mi = 0; mi < 2; mi++)
#pragma unroll
            for (int kk = 0; kk < 2; kk++) {
                float* p = Sc + rowbase[mi] + s0 + kk * 32 + lq * 8;
                half8 h = af[mi][kk];
                ((float4*)p)[0] = make_float4((float)h[0], (float)h[1], (float)h[2], (float)h[3]);
                ((float4*)p)[1] = make_float4((float)h[4], (float)h[5], (float)h[6], (float)h[7]);
            }
#pragma unroll
        for (int kk = 0; kk < 2; kk++)
#pragma unroll
            for (int ni = 0; ni < 16; ni++) {
                half8 bf = *(const half8*)&Bs[rbk[kk] + ni * 128];
#pragma unroll
                for (int mi = 0; mi < 2; mi++)
                    acc[mi][ni] = __builtin_amdgcn_mfma_f32_16x16x32_f16(af[mi][kk], bf, acc[mi][ni], 0, 0, 0);
            }
        __syncthreads();
    }

    float* P = part + (size_t)ks * 4194304 + (size_t)b * 1048576;
#pragma unroll
    for (int mi = 0; mi < 2; mi++)
#pragma unroll
        for (int ni = 0; ni < 16; ni++)
#pragma unroll
            for (int r = 0; r < 4; r++) {
                int row = t0 + wave * 32 + mi * 16 + lq * 4 + r;
                int col = ni * 16 + lm;
                P[(size_t)row * 256 + col] = acc[mi][ni][r];
            }
}

// ---------------- K5: reduce 4 split-K partials -> context ----------------
__global__ void k_red(const float* __restrict__ part, float* __restrict__ out) {
    size_t i = (size_t)blockIdx.x * 256 + threadIdx.x;  // float4 index, N4 = 1048576
    const float4* p = (const float4*)part;
    float4 a = p[i];
    float4 b = p[i + 1048576];
    float4 c = p[i + 2097152];
    float4 d = p[i + 3145728];
    a.x += b.x + c.x + d.x;
    a.y += b.y + c.y + d.y;
    a.z += b.z + c.z + d.z;
    a.w += b.w + c.w + d.w;
    ((float4*)out)[i] = a;
}

extern "C" void kernel_launch(void* const* d_in, const int* in_sizes, int n_in,
                              void* d_out, int out_size, void* d_ws, size_t ws_size,
                              hipStream_t stream) {
    const float* h_t = (const float*)d_in[0];   // 4*4096*256
    const float* h_s = (const float*)d_in[1];   // 4*4096*256
    const int*   m_s = (const int*)d_in[2];     // 4*4096
    const float* W   = (const float*)d_in[3];   // 256*256

    float* out = (float*)d_out;
    char* ws = (char*)d_ws;
    f16* h_t16 = (f16*)(ws);
    f16* h_s16 = (f16*)(ws + 8388608);
    f16* h_sT  = (f16*)(ws + 16777216);
    f16* en16  = (f16*)(ws + 25165824);
    f16* W16   = (f16*)(ws + 33554432);
    float* rsum = (float*)(ws + 33685504);   // 16384 floats
    float* part = (float*)(ws + 33816576);   // 4 * 16.78MB

    float* ctx = out;              // 4*4096*256 = 4194304
    float* sc  = out + 4194304;    // 4*4096*4096

    hipMemsetAsync(rsum, 0, 16384 * sizeof(float), stream);
    k_cvt<<<2048, 256, 0, stream>>>(h_t, h_t16, 524288);
    k_cvt<<<32, 256, 0, stream>>>(W, W16, 8192);
    k_hs<<<1024, 256, 0, stream>>>(h_s, h_s16, h_sT);
    k_energy<<<256, 256, 0, stream>>>(h_s16, W16, en16);
    k_scores<<<4096, 256, 0, stream>>>(h_t16, en16, m_s, sc, rsum);
    k_ctx<<<512, 256, 0, stream>>>(h_sT, sc, rsum, part);
    k_red<<<4096, 256, 0, stream>>>(part, ctx);
}